// Round 2
// baseline (1644.541 us; speedup 1.0000x reference)
//
#include <hip/hip_runtime.h>
#include <math.h>

#define T_  20
#define BN  3200
#define H   128
#define N3H 384
#define DOUT 2
#define JW  400          // BN/8 bitpack words (bytes) per t per column

typedef unsigned char u8;

// mask may arrive as 1-byte bool or canonicalized int32; flag=1 -> u8.
__device__ __forceinline__ bool getm(const u8* m8, const int* m32, int fl, int idx) {
    return fl ? (m8[idx] != 0) : (m32[idx] != 0);
}

// ---------------------------------------------------------------- K0: detect mask dtype
__global__ void k_detect(const u8* __restrict__ mask, int* __restrict__ flag) {
    int i = blockIdx.x * 256 + threadIdx.x;          // over T_*BN bytes
    bool hit = (i < T_ * BN) && (i & 3) && (mask[i] != 0);
    if (__any(hit) && (threadIdx.x & 63) == 0) atomicOr(flag, 1);
}

// ---------------------------------------------------------------- K1: compact active rows per t
__global__ void k_compact(const u8* __restrict__ m8, const int* __restrict__ m32,
                          const int* __restrict__ flag,
                          int* __restrict__ act_idx, int* __restrict__ act_cnt) {
    int t = blockIdx.x, fl = *flag;
    for (int j = threadIdx.x; j < BN; j += blockDim.x) {
        if (getm(m8, m32, fl, t * BN + j)) {
            int pos = atomicAdd(&act_cnt[t], 1);
            act_idx[t * BN + pos] = j;   // unordered: all downstream sums order-independent
        }
    }
}

// ---------------------------------------------------------------- K2: column degree + bitpack active-A
// block: (cb: 256 cols, rc: chunk of 128 active rows, t)
__global__ __launch_bounds__(256) void k_deg_pack(const int* __restrict__ A,
                                                  const int* __restrict__ act_idx,
                                                  const int* __restrict__ act_cnt,
                                                  u8* __restrict__ A1,
                                                  int* __restrict__ deg) {
    int t = blockIdx.z, rc = blockIdx.y;
    int c = blockIdx.x * 256 + threadIdx.x;
    if (c >= BN) return;
    int nact = act_cnt[t];
    int start = rc * 128;
    if (start >= nact) return;
    int end = min(start + 128, nact);
    const int* At = A + (size_t)t * BN * BN;
    const int* ai = act_idx + t * BN;
    int cnt = 0;
    for (int jb = start; jb < end; jb += 8) {
        unsigned byte = 0;
        int lim = min(8, end - jb);
        #pragma unroll
        for (int q = 0; q < 8; ++q) {
            if (q < lim) {
                int j = ai[jb + q];                       // uniform -> scalar load
                int a = At[(size_t)j * BN + c];           // coalesced 1KB/wave
                cnt += a;
                byte |= (unsigned)a << q;
            }
        }
        A1[((size_t)t * JW + (jb >> 3)) * BN + c] = (u8)byte;
    }
    atomicAdd(&deg[t * BN + c], cnt);
}

// ---------------------------------------------------------------- K3: dinv = m ? rsqrt(deg+1) : 0
__global__ void k_dinv(const int* __restrict__ deg, const u8* __restrict__ m8,
                       const int* __restrict__ m32, const int* __restrict__ flag,
                       float* __restrict__ dinv) {
    int i = blockIdx.x * 256 + threadIdx.x;          // over T_*BN
    int fl = *flag;
    dinv[i] = getm(m8, m32, fl, i) ? rsqrtf((float)(deg[i] + 1)) : 0.f;
}

// ---------------------------------------------------------------- K4: compacted u0,u1 (u = dinv * x)
__global__ void k_u(const float* __restrict__ x, const float* __restrict__ dinv,
                    const int* __restrict__ act_idx, const int* __restrict__ act_cnt,
                    float* __restrict__ u0c, float* __restrict__ u1c) {
    int idx = blockIdx.x * 256 + threadIdx.x;        // over T_*BN
    int t = idx / BN, jj = idx - t * BN;
    float v0 = 0.f, v1 = 0.f;
    if (jj < act_cnt[t]) {
        int j = act_idx[t * BN + jj];
        float d = dinv[t * BN + j];
        v0 = d * x[(size_t)(t * BN + j) * 2];
        v1 = d * x[(size_t)(t * BN + j) * 2 + 1];
    }
    u0c[idx] = v0;
    u1c[idx] = v1;
}

// ---------------------------------------------------------------- K5: c0[i],c1[i] = sum_j A1[j,i]*u{0,1}[j]
// block: (cb: 1024 cols via uchar4, js: 1/8 of row-words, t)
__global__ __launch_bounds__(256) void k_c(const u8* __restrict__ A1,
                                           const int* __restrict__ act_cnt,
                                           const float* __restrict__ u0c,
                                           const float* __restrict__ u1c,
                                           float* __restrict__ c0g,
                                           float* __restrict__ c1g) {
    int t = blockIdx.z, js = blockIdx.y;
    int c = blockIdx.x * 1024 + threadIdx.x * 4;
    if (c >= BN) return;
    int nactp = (act_cnt[t] + 7) >> 3;
    int jw0 = js * (JW / 8), jw1 = min(jw0 + JW / 8, nactp);
    if (jw0 >= jw1) return;
    const u8* base = A1 + (size_t)t * JW * BN;
    const float* U0 = u0c + t * BN;
    const float* U1 = u1c + t * BN;
    float s0[4] = {0.f, 0.f, 0.f, 0.f}, s1[4] = {0.f, 0.f, 0.f, 0.f};
    for (int jw = jw0; jw < jw1; ++jw) {
        uchar4 aa = *(const uchar4*)(base + (size_t)jw * BN + c);
        unsigned bb[4] = {aa.x, aa.y, aa.z, aa.w};
        const float* Up0 = U0 + jw * 8;
        const float* Up1 = U1 + jw * 8;
        #pragma unroll
        for (int jb = 0; jb < 8; ++jb) {
            float w0 = Up0[jb], w1 = Up1[jb];        // uniform -> scalar loads
            #pragma unroll
            for (int k = 0; k < 4; ++k) {
                if ((bb[k] >> jb) & 1) { s0[k] += w0; s1[k] += w1; }
            }
        }
    }
    #pragma unroll
    for (int k = 0; k < 4; ++k) {
        atomicAdd(&c0g[t * BN + c + k], s0[k]);
        atomicAdd(&c1g[t * BN + c + k], s1[k]);
    }
}

// ---------------------------------------------------------------- K6: GI = relu(e0*Wg0 + e1*Wg1 + bg) @ W_ih + b_ih
// 16 rows/block, 128 threads (3 output cols each). Inactive rows skipped (GRU never reads them).
__global__ __launch_bounds__(128) void k_gi(const float* __restrict__ dinv,
                                            const float* __restrict__ c0g,
                                            const float* __restrict__ c1g,
                                            const float* __restrict__ x,
                                            const float* __restrict__ Wg,
                                            const float* __restrict__ bg,
                                            const u8* __restrict__ m8,
                                            const int* __restrict__ m32,
                                            const int* __restrict__ flag,
                                            const float* __restrict__ Wih,
                                            const float* __restrict__ bih,
                                            float* __restrict__ GI) {
    int row0 = blockIdx.x * 16;
    int tid = threadIdx.x;
    __shared__ float gs[16][H];
    __shared__ float e0s[16], e1s[16];
    __shared__ int msh[16];
    if (tid < 16) {
        int row = row0 + tid;
        msh[tid] = getm(m8, m32, *flag, row) ? 1 : 0;
        float d = dinv[row];
        e0s[tid] = d * (c0g[row] + d * x[(size_t)row * 2]);
        e1s[tid] = d * (c1g[row] + d * x[(size_t)row * 2 + 1]);
    }
    __syncthreads();
    float wg0 = Wg[tid], wg1 = Wg[H + tid], bgv = bg[tid];
    #pragma unroll
    for (int r = 0; r < 16; ++r)
        gs[r][tid] = fmaxf(e0s[r] * wg0 + e1s[r] * wg1 + bgv, 0.f);
    __syncthreads();

    float acc[16][3];
    #pragma unroll
    for (int r = 0; r < 16; ++r) { acc[r][0] = 0.f; acc[r][1] = 0.f; acc[r][2] = 0.f; }

    for (int k = 0; k < H; k += 4) {
        float w[4][3];
        #pragma unroll
        for (int kk = 0; kk < 4; ++kk) {
            const float* wr = Wih + (size_t)(k + kk) * N3H;
            w[kk][0] = wr[tid]; w[kk][1] = wr[128 + tid]; w[kk][2] = wr[256 + tid];
        }
        #pragma unroll
        for (int r = 0; r < 16; ++r) {
            if (!msh[r]) continue;                   // uniform branch
            float4 g4 = *(const float4*)&gs[r][k];   // uniform addr -> LDS broadcast
            acc[r][0] += g4.x * w[0][0] + g4.y * w[1][0] + g4.z * w[2][0] + g4.w * w[3][0];
            acc[r][1] += g4.x * w[0][1] + g4.y * w[1][1] + g4.z * w[2][1] + g4.w * w[3][1];
            acc[r][2] += g4.x * w[0][2] + g4.y * w[1][2] + g4.z * w[2][2] + g4.w * w[3][2];
        }
    }
    float b0 = bih[tid], b1 = bih[128 + tid], b2 = bih[256 + tid];
    #pragma unroll
    for (int r = 0; r < 16; ++r) {
        if (!msh[r]) continue;
        size_t bbase = (size_t)(row0 + r) * N3H;
        GI[bbase + tid]       = acc[r][0] + b0;
        GI[bbase + 128 + tid] = acc[r][1] + b1;
        GI[bbase + 256 + tid] = acc[r][2] + b2;
    }
}

// ---------------------------------------------------------------- K7: sequential GRU over t + fc output
// 16 rows/block, 256 threads: tid&127 = hidden unit, tid>>7 = row-half.
__global__ __launch_bounds__(256) void k_gru(const float* __restrict__ GI,
                                             const float* __restrict__ Whh,
                                             const float* __restrict__ bhh,
                                             const u8* __restrict__ m8,
                                             const int* __restrict__ m32,
                                             const int* __restrict__ flag,
                                             const float* __restrict__ Wfc,
                                             const float* __restrict__ bfc,
                                             float* __restrict__ out) {
    int row0 = blockIdx.x * 16;
    int tid = threadIdx.x;
    int u = tid & 127, half = tid >> 7;
    int fl = *flag;
    __shared__ float hs[16][H];
    __shared__ int ms[16];
    __shared__ float red[4][8][2];
    for (int idx = tid; idx < 16 * H; idx += 256) (&hs[0][0])[idx] = 0.f;

    float b0 = bhh[u], b1 = bhh[128 + u], b2 = bhh[256 + u];
    float wf0 = Wfc[u * 2], wf1 = Wfc[u * 2 + 1];
    float bf0 = bfc[0], bf1 = bfc[1];
    int wv = tid >> 6;   // wave id 0..3

    for (int t = 0; t < T_; ++t) {
        if (tid < 16) ms[tid] = getm(m8, m32, fl, t * BN + row0 + tid) ? 1 : 0;
        __syncthreads();

        float a0[8], a1[8], a2[8];
        #pragma unroll
        for (int r = 0; r < 8; ++r) { a0[r] = 0.f; a1[r] = 0.f; a2[r] = 0.f; }

        for (int k = 0; k < H; k += 4) {
            float w[4][3];
            #pragma unroll
            for (int kk = 0; kk < 4; ++kk) {
                const float* wr = Whh + (size_t)(k + kk) * N3H;
                w[kk][0] = wr[u]; w[kk][1] = wr[128 + u]; w[kk][2] = wr[256 + u];
            }
            #pragma unroll
            for (int r = 0; r < 8; ++r) {
                int gr = half * 8 + r;
                if (!ms[gr]) continue;               // uniform branch
                float4 h4 = *(const float4*)&hs[gr][k];   // uniform addr -> broadcast
                a0[r] += h4.x * w[0][0] + h4.y * w[1][0] + h4.z * w[2][0] + h4.w * w[3][0];
                a1[r] += h4.x * w[0][1] + h4.y * w[1][1] + h4.z * w[2][1] + h4.w * w[3][1];
                a2[r] += h4.x * w[0][2] + h4.y * w[1][2] + h4.z * w[2][2] + h4.w * w[3][2];
            }
        }
        #pragma unroll
        for (int r = 0; r < 8; ++r) {
            int gr = half * 8 + r;
            if (!ms[gr]) continue;
            size_t gb = ((size_t)t * BN + row0 + gr) * N3H;
            float ir = GI[gb + u], iz = GI[gb + 128 + u], ig = GI[gb + 256 + u];
            float rg = 1.f / (1.f + expf(-(ir + a0[r] + b0)));
            float zg = 1.f / (1.f + expf(-(iz + a1[r] + b1)));
            float ng = tanhf(ig + rg * (a2[r] + b2));
            hs[gr][u] = (1.f - zg) * ng + zg * hs[gr][u];   // own element: no race
        }
        // out[row, t, :] = h . W_fc + b_fc  (post-update h, all 16 rows)
        #pragma unroll
        for (int r = 0; r < 8; ++r) {
            int gr = half * 8 + r;
            float hv = hs[gr][u];
            float p0 = hv * wf0, p1 = hv * wf1;
            for (int o = 32; o > 0; o >>= 1) { p0 += __shfl_down(p0, o); p1 += __shfl_down(p1, o); }
            if ((tid & 63) == 0) { red[wv][r][0] = p0; red[wv][r][1] = p1; }
        }
        __syncthreads();
        if (tid < 32) {
            int gr = tid >> 1, d = tid & 1;
            int wbase = (gr >> 3) * 2, rr = gr & 7;
            float val = red[wbase][rr][d] + red[wbase + 1][rr][d] + (d ? bf1 : bf0);
            out[((size_t)(row0 + gr) * T_ + t) * DOUT + d] = val;
        }
        __syncthreads();
    }
}

// ---------------------------------------------------------------- launch
extern "C" void kernel_launch(void* const* d_in, const int* in_sizes, int n_in,
                              void* d_out, int out_size, void* d_ws, size_t ws_size,
                              hipStream_t stream) {
    const float* x    = (const float*)d_in[0];
    const int*   A    = (const int*)d_in[1];
    const u8*    m8   = (const u8*)d_in[2];
    const int*   m32  = (const int*)d_in[2];
    const float* Wg   = (const float*)d_in[4];
    const float* bg   = (const float*)d_in[5];
    const float* Wih  = (const float*)d_in[6];
    const float* bih  = (const float*)d_in[7];
    const float* Whh  = (const float*)d_in[8];
    const float* bhh  = (const float*)d_in[9];
    const float* Wfc  = (const float*)d_in[10];
    const float* bfc  = (const float*)d_in[11];
    float* out = (float*)d_out;

    char* ws = (char*)d_ws;
    size_t off = 0;
    auto alloc = [&](size_t bytes) {
        void* p = ws + off;
        off += (bytes + 255) & ~(size_t)255;
        return p;
    };
    // zero-init region (one memset): flag, act_cnt, deg, c0, c1
    int*   flag    = (int*)alloc(4);
    int*   act_cnt = (int*)alloc(T_ * 4);
    int*   deg     = (int*)alloc((size_t)T_ * BN * 4);
    float* c0g     = (float*)alloc((size_t)T_ * BN * 4);
    float* c1g     = (float*)alloc((size_t)T_ * BN * 4);
    size_t zbytes = off;
    int*   act_idx = (int*)alloc((size_t)T_ * BN * 4);
    float* dinv    = (float*)alloc((size_t)T_ * BN * 4);
    float* u0c     = (float*)alloc((size_t)T_ * BN * 4);
    float* u1c     = (float*)alloc((size_t)T_ * BN * 4);
    u8*    A1      = (u8*)alloc((size_t)T_ * JW * BN);        // 25.6 MB bitpacked A
    float* GI      = (float*)alloc((size_t)T_ * BN * N3H * 4); // 98.3 MB

    hipMemsetAsync(ws, 0, zbytes, stream);
    k_detect<<<(T_ * BN + 255) / 256, 256, 0, stream>>>(m8, flag);
    k_compact<<<T_, 256, 0, stream>>>(m8, m32, flag, act_idx, act_cnt);
    k_deg_pack<<<dim3((BN + 255) / 256, BN / 128, T_), 256, 0, stream>>>(A, act_idx, act_cnt, A1, deg);
    k_dinv<<<(T_ * BN) / 256, 256, 0, stream>>>(deg, m8, m32, flag, dinv);
    k_u<<<(T_ * BN) / 256, 256, 0, stream>>>(x, dinv, act_idx, act_cnt, u0c, u1c);
    k_c<<<dim3(4, 8, T_), 256, 0, stream>>>(A1, act_cnt, u0c, u1c, c0g, c1g);
    k_gi<<<(T_ * BN) / 16, 128, 0, stream>>>(dinv, c0g, c1g, x, Wg, bg, m8, m32, flag, Wih, bih, GI);
    k_gru<<<BN / 16, 256, 0, stream>>>(GI, Whh, bhh, m8, m32, flag, Wfc, bfc, out);
}

// Round 6
// 1638.704 us; speedup vs baseline: 1.0036x; 1.0036x over previous
//
#include <hip/hip_runtime.h>
#include <math.h>

#define T_  20
#define BN  3200
#define H   128
#define N3H 384
#define DOUT 2
#define JW  400          // BN/8 bitpack bytes per t per column (worst case)

typedef unsigned char u8;

// mask may arrive as 1-byte bool or canonicalized int32; flag=1 -> u8.
__device__ __forceinline__ bool getm(const u8* m8, const int* m32, int fl, int idx) {
    return fl ? (m8[idx] != 0) : (m32[idx] != 0);
}

// ---------------------------------------------------------------- K1: detect dtype (local) + compact active rows per t
__global__ __launch_bounds__(256) void k_compact(const u8* __restrict__ m8,
                                                 const int* __restrict__ m32,
                                                 int* __restrict__ flag,
                                                 int* __restrict__ act_idx,
                                                 int* __restrict__ act_cnt) {
    int t = blockIdx.x, tid = threadIdx.x;
    __shared__ int lf;
    if (tid == 0) lf = 0;
    __syncthreads();
    // u8 bool mask: ~1600 ones among 3200 bytes -> some byte at off%4!=0 is set.
    // int32 mask (0/1): bytes at off%4!=0 are always 0.
    bool hit = false;
    for (int j = tid; j < BN; j += 256) {
        if ((j & 3) && m8[t * BN + j]) hit = true;   // (t*BN)%4==0 so idx&3==j&3
    }
    if (__any(hit) && (tid & 63) == 0) atomicOr(&lf, 1);
    __syncthreads();
    int fl = lf;
    if (tid == 0 && fl) atomicOr(flag, 1);           // global flag for later kernels
    for (int j = tid; j < BN; j += 256) {
        if (getm(m8, m32, fl, t * BN + j)) {
            int pos = atomicAdd(&act_cnt[t], 1);     // wave-aggregated by compiler
            act_idx[t * BN + pos] = j;               // unordered: sums order-independent
        }
    }
}

// ---------------------------------------------------------------- K2: column degree + bitpack active-A
// grid (4 colblocks x 13 rowchunks x T), 256 thr; thread = 4 cols via int4.
#define RCH 256
__global__ __launch_bounds__(256) void k_deg_pack(const int* __restrict__ A,
                                                  const int* __restrict__ act_idx,
                                                  const int* __restrict__ act_cnt,
                                                  u8* __restrict__ A1,
                                                  int* __restrict__ deg) {
    int t = blockIdx.z;
    int nact = act_cnt[t];
    int start = blockIdx.y * RCH;
    if (start >= nact) return;                        // uniform: whole block exits
    int n = min(RCH, nact - start);
    __shared__ int ai_s[RCH];
    int tid = threadIdx.x;
    if (tid < n) ai_s[tid] = act_idx[t * BN + start + tid];
    __syncthreads();

    int c = (blockIdx.x * 256 + tid) * 4;
    if (c >= BN) return;                              // after the only barrier: safe
    const int* At = A + (size_t)t * BN * BN;
    u8* A1t = A1 + ((size_t)t * JW + (start >> 3)) * BN + c;
    int cnt0 = 0, cnt1 = 0, cnt2 = 0, cnt3 = 0;
    int n8 = n & ~7;
    int jb = 0;
    for (; jb < n8; jb += 8) {
        unsigned b0 = 0, b1 = 0, b2 = 0, b3 = 0;
        #pragma unroll
        for (int q = 0; q < 8; ++q) {
            int j = ai_s[jb + q];
            int4 aa = *(const int4*)(At + (size_t)j * BN + c);   // 1KB/wave
            cnt0 += aa.x; b0 |= (unsigned)aa.x << q;
            cnt1 += aa.y; b1 |= (unsigned)aa.y << q;
            cnt2 += aa.z; b2 |= (unsigned)aa.z << q;
            cnt3 += aa.w; b3 |= (unsigned)aa.w << q;
        }
        uchar4 pk; pk.x = (u8)b0; pk.y = (u8)b1; pk.z = (u8)b2; pk.w = (u8)b3;
        *(uchar4*)(A1t + (size_t)(jb >> 3) * BN) = pk;
    }
    if (jb < n) {                                     // tail (n not multiple of 8)
        unsigned b0 = 0, b1 = 0, b2 = 0, b3 = 0;
        for (int q = 0; q < n - jb; ++q) {
            int j = ai_s[jb + q];
            int4 aa = *(const int4*)(At + (size_t)j * BN + c);
            cnt0 += aa.x; b0 |= (unsigned)aa.x << q;
            cnt1 += aa.y; b1 |= (unsigned)aa.y << q;
            cnt2 += aa.z; b2 |= (unsigned)aa.z << q;
            cnt3 += aa.w; b3 |= (unsigned)aa.w << q;
        }
        uchar4 pk; pk.x = (u8)b0; pk.y = (u8)b1; pk.z = (u8)b2; pk.w = (u8)b3;
        *(uchar4*)(A1t + (size_t)(jb >> 3) * BN) = pk;
    }
    atomicAdd(&deg[t * BN + c], cnt0);
    atomicAdd(&deg[t * BN + c + 1], cnt1);
    atomicAdd(&deg[t * BN + c + 2], cnt2);
    atomicAdd(&deg[t * BN + c + 3], cnt3);
}

// ---------------------------------------------------------------- K3: dinv (all rows) + compacted u0,u1
__global__ __launch_bounds__(256) void k_dinv_u(const int* __restrict__ deg,
                                                const u8* __restrict__ m8,
                                                const int* __restrict__ m32,
                                                const int* __restrict__ flag,
                                                const float* __restrict__ x,
                                                const int* __restrict__ act_idx,
                                                const int* __restrict__ act_cnt,
                                                float* __restrict__ dinv,
                                                float* __restrict__ u0c,
                                                float* __restrict__ u1c) {
    int idx = blockIdx.x * 256 + threadIdx.x;        // over T_*BN
    int fl = *flag;
    int t = idx / BN, r = idx - t * BN;
    dinv[idx] = getm(m8, m32, fl, idx) ? rsqrtf((float)(deg[idx] + 1)) : 0.f;
    float v0 = 0.f, v1 = 0.f;
    if (r < act_cnt[t]) {
        int j = act_idx[idx];                        // = act_idx[t*BN + r]
        float d = rsqrtf((float)(deg[t * BN + j] + 1));  // j active => mask true
        v0 = d * x[(size_t)(t * BN + j) * 2];
        v1 = d * x[(size_t)(t * BN + j) * 2 + 1];
    }
    u0c[idx] = v0;
    u1c[idx] = v1;
}

// ---------------------------------------------------------------- K4: c0[i],c1[i] = sum_j A1[j,i]*u{0,1}[j]
#define JSL 25            // 16 slices x 25 words = 400 >= worst-case nactp
__global__ __launch_bounds__(256) void k_c(const u8* __restrict__ A1,
                                           const int* __restrict__ act_cnt,
                                           const float* __restrict__ u0c,
                                           const float* __restrict__ u1c,
                                           float* __restrict__ c0g,
                                           float* __restrict__ c1g) {
    int t = blockIdx.z, js = blockIdx.y;
    int c = blockIdx.x * 1024 + threadIdx.x * 4;
    if (c >= BN) return;
    int nactp = (act_cnt[t] + 7) >> 3;
    int jw0 = js * JSL, jw1 = min(jw0 + JSL, nactp);
    if (jw0 >= jw1) return;
    const u8* base = A1 + (size_t)t * JW * BN;
    const float* U0 = u0c + t * BN;
    const float* U1 = u1c + t * BN;
    float s0[4] = {0.f, 0.f, 0.f, 0.f}, s1[4] = {0.f, 0.f, 0.f, 0.f};
    for (int jw = jw0; jw < jw1; ++jw) {
        uchar4 aa = *(const uchar4*)(base + (size_t)jw * BN + c);
        unsigned bb[4] = {aa.x, aa.y, aa.z, aa.w};
        const float* Up0 = U0 + jw * 8;
        const float* Up1 = U1 + jw * 8;
        #pragma unroll
        for (int jb = 0; jb < 8; ++jb) {
            float w0 = Up0[jb], w1 = Up1[jb];        // block-uniform -> scalar loads
            #pragma unroll
            for (int k = 0; k < 4; ++k) {
                if ((bb[k] >> jb) & 1) { s0[k] += w0; s1[k] += w1; }
            }
        }
    }
    #pragma unroll
    for (int k = 0; k < 4; ++k) {
        atomicAdd(&c0g[t * BN + c + k], s0[k]);
        atomicAdd(&c1g[t * BN + c + k], s1[k]);
    }
}

// ---------------------------------------------------------------- K5: GI rows for ACTIVE nodes only (compacted)
// grid (100 slotblocks x T), 384 thr: thread = one of 384 output cols; 32 active rows/block.
__global__ __launch_bounds__(384) void k_gi(const float* __restrict__ dinv,
                                            const float* __restrict__ c0g,
                                            const float* __restrict__ c1g,
                                            const float* __restrict__ x,
                                            const float* __restrict__ Wg,
                                            const float* __restrict__ bg,
                                            const int* __restrict__ act_idx,
                                            const int* __restrict__ act_cnt,
                                            const float* __restrict__ Wih,
                                            const float* __restrict__ bih,
                                            float* __restrict__ GI) {
    int t = blockIdx.y;
    int nact = act_cnt[t];
    int sb = blockIdx.x * 32;
    if (sb >= nact) return;                           // uniform
    int ns = min(32, nact - sb);
    __shared__ float gs[32][H];                       // 16 KB
    __shared__ float e0s[32], e1s[32];
    __shared__ int ar[32];
    int tid = threadIdx.x;
    if (tid < 32) {
        int row = 0; float e0 = 0.f, e1 = 0.f;
        if (tid < ns) {
            row = act_idx[t * BN + sb + tid];
            int gi = t * BN + row;
            float d = dinv[gi];
            e0 = d * (c0g[gi] + d * x[(size_t)gi * 2]);
            e1 = d * (c1g[gi] + d * x[(size_t)gi * 2 + 1]);
        }
        ar[tid] = row; e0s[tid] = e0; e1s[tid] = e1;
    }
    __syncthreads();
    for (int u2 = tid; u2 < 32 * H; u2 += 384) {      // g = relu(e0*Wg0 + e1*Wg1 + bg)
        int r = u2 >> 7, h = u2 & 127;
        gs[r][h] = fmaxf(e0s[r] * Wg[h] + e1s[r] * Wg[H + h] + bg[h], 0.f);
    }
    __syncthreads();

    float acc[32];
    #pragma unroll
    for (int r = 0; r < 32; ++r) acc[r] = 0.f;
    for (int k = 0; k < H; k += 4) {
        float w0 = Wih[(size_t)k * N3H + tid];        // 1x Wih per block total
        float w1 = Wih[(size_t)(k + 1) * N3H + tid];
        float w2 = Wih[(size_t)(k + 2) * N3H + tid];
        float w3 = Wih[(size_t)(k + 3) * N3H + tid];
        #pragma unroll
        for (int r = 0; r < 32; ++r) {
            float4 g4 = *(const float4*)&gs[r][k];    // LDS broadcast
            acc[r] += g4.x * w0 + g4.y * w1 + g4.z * w2 + g4.w * w3;
        }
    }
    float bb = bih[tid];
    #pragma unroll
    for (int r = 0; r < 32; ++r) {
        if (r < ns)                                   // uniform bound
            GI[((size_t)t * BN + ar[r]) * N3H + tid] = acc[r] + bb;
    }
}

// ---------------------------------------------------------------- K6: sequential GRU over t + fc output
// 200 blocks x 384 thr (6 waves): thread = one Whh output col; 16 rows/block.
// Per t: GI prefetch (hidden under matmul) -> masked gh matmul -> pointwise -> out.
__global__ __launch_bounds__(384) void k_gru(const float* __restrict__ GI,
                                             const float* __restrict__ Whh,
                                             const float* __restrict__ bhh,
                                             const u8* __restrict__ m8,
                                             const int* __restrict__ m32,
                                             const int* __restrict__ flag,
                                             const float* __restrict__ Wfc,
                                             const float* __restrict__ bfc,
                                             float* __restrict__ out) {
    int row0 = blockIdx.x * 16;
    int tid = threadIdx.x;
    int fl = *flag;
    __shared__ float hs[16][H];                       // 8 KB   (h state across t)
    __shared__ float ghs[16][N3H];                    // 24 KB  (gh per step)
    __shared__ float bhs[N3H];
    __shared__ int ms[16];
    for (int i = tid; i < 16 * H; i += 384) (&hs[0][0])[i] = 0.f;
    if (tid < N3H) bhs[tid] = bhh[tid];
    int lane = tid & 63, wv = tid >> 6;
    float wfa0 = Wfc[lane * 2],        wfa1 = Wfc[lane * 2 + 1];
    float wfb0 = Wfc[(lane + 64) * 2], wfb1 = Wfc[(lane + 64) * 2 + 1];
    float bf0 = bfc[0], bf1 = bfc[1];

    for (int t = 0; t < T_; ++t) {
        if (tid < 16) ms[tid] = getm(m8, m32, fl, t * BN + row0 + tid) ? 1 : 0;
        __syncthreads();
        int mrl[16];
        #pragma unroll
        for (int r = 0; r < 16; ++r) mrl[r] = ms[r];

        // --- GI prefetch (issued before the matmul; latency hidden under it)
        float pir[6], piz[6], pig[6];
        #pragma unroll
        for (int ii = 0; ii < 6; ++ii) {
            pir[ii] = 0.f; piz[ii] = 0.f; pig[ii] = 0.f;
            int i5 = tid + ii * 384;
            if (i5 < 16 * H) {
                int r = i5 >> 7, u = i5 & 127;
                if (ms[r]) {                          // guarded: half the HBM traffic
                    size_t gb = ((size_t)t * BN + row0 + r) * N3H;
                    pir[ii] = GI[gb + u];
                    piz[ii] = GI[gb + 128 + u];
                    pig[ii] = GI[gb + 256 + u];
                }
            }
        }

        // --- gh = h @ Whh, active rows only (uniform branch per row)
        float acc[16];
        #pragma unroll
        for (int r = 0; r < 16; ++r) acc[r] = 0.f;
        for (int k = 0; k < H; k += 4) {
            float w0 = Whh[(size_t)k * N3H + tid];    // 1x Whh per block per t (L2)
            float w1 = Whh[(size_t)(k + 1) * N3H + tid];
            float w2 = Whh[(size_t)(k + 2) * N3H + tid];
            float w3 = Whh[(size_t)(k + 3) * N3H + tid];
            #pragma unroll
            for (int r = 0; r < 16; ++r) {
                if (mrl[r]) {                         // all lanes agree
                    float4 h4 = *(const float4*)&hs[r][k];   // broadcast
                    acc[r] += h4.x * w0 + h4.y * w1 + h4.z * w2 + h4.w * w3;
                }
            }
        }
        #pragma unroll
        for (int r = 0; r < 16; ++r) ghs[r][tid] = acc[r];
        __syncthreads();

        // --- pointwise GRU update from prefetched GI
        #pragma unroll
        for (int ii = 0; ii < 6; ++ii) {
            int i5 = tid + ii * 384;
            if (i5 < 16 * H) {
                int r = i5 >> 7, u = i5 & 127;
                if (ms[r]) {
                    float hr = ghs[r][u] + bhs[u];
                    float hz = ghs[r][128 + u] + bhs[128 + u];
                    float hg = ghs[r][256 + u] + bhs[256 + u];
                    float rg = 1.f / (1.f + expf(-(pir[ii] + hr)));
                    float zg = 1.f / (1.f + expf(-(piz[ii] + hz)));
                    float ng = tanhf(pig[ii] + rg * hg);
                    hs[r][u] = (1.f - zg) * ng + zg * hs[r][u];
                }
            }
        }
        __syncthreads();

        // --- out[row, t, :] = h . Wfc + bfc (post-update h, all rows)
        for (int r = wv; r < 16; r += 6) {
            float h0 = hs[r][lane], h1 = hs[r][lane + 64];
            float p0 = h0 * wfa0 + h1 * wfb0;
            float p1 = h0 * wfa1 + h1 * wfb1;
            for (int o = 32; o > 0; o >>= 1) { p0 += __shfl_down(p0, o); p1 += __shfl_down(p1, o); }
            if (lane == 0) {
                out[((size_t)(row0 + r) * T_ + t) * DOUT]     = p0 + bf0;
                out[((size_t)(row0 + r) * T_ + t) * DOUT + 1] = p1 + bf1;
            }
        }
        __syncthreads();
    }
}

// ---------------------------------------------------------------- launch
extern "C" void kernel_launch(void* const* d_in, const int* in_sizes, int n_in,
                              void* d_out, int out_size, void* d_ws, size_t ws_size,
                              hipStream_t stream) {
    const float* x    = (const float*)d_in[0];
    const int*   A    = (const int*)d_in[1];
    const u8*    m8   = (const u8*)d_in[2];
    const int*   m32  = (const int*)d_in[2];
    const float* Wg   = (const float*)d_in[4];
    const float* bg   = (const float*)d_in[5];
    const float* Wih  = (const float*)d_in[6];
    const float* bih  = (const float*)d_in[7];
    const float* Whh  = (const float*)d_in[8];
    const float* bhh  = (const float*)d_in[9];
    const float* Wfc  = (const float*)d_in[10];
    const float* bfc  = (const float*)d_in[11];
    float* out = (float*)d_out;

    char* ws = (char*)d_ws;
    size_t off = 0;
    auto alloc = [&](size_t bytes) {
        void* p = ws + off;
        off += (bytes + 255) & ~(size_t)255;
        return p;
    };
    // zero-init region (one small memset): flag, act_cnt, deg, c0, c1
    int*   flag    = (int*)alloc(4);
    int*   act_cnt = (int*)alloc(T_ * 4);
    int*   deg     = (int*)alloc((size_t)T_ * BN * 4);
    float* c0g     = (float*)alloc((size_t)T_ * BN * 4);
    float* c1g     = (float*)alloc((size_t)T_ * BN * 4);
    size_t zbytes = off;
    int*   act_idx = (int*)alloc((size_t)T_ * BN * 4);
    float* dinv    = (float*)alloc((size_t)T_ * BN * 4);
    float* u0c     = (float*)alloc((size_t)T_ * BN * 4);
    float* u1c     = (float*)alloc((size_t)T_ * BN * 4);
    u8*    A1      = (u8*)alloc((size_t)T_ * JW * BN);         // 25.6 MB bitpacked A
    float* GI      = (float*)alloc((size_t)T_ * BN * N3H * 4); // 98.3 MB (active rows written)

    hipMemsetAsync(ws, 0, zbytes, stream);
    k_compact<<<T_, 256, 0, stream>>>(m8, m32, flag, act_idx, act_cnt);
    k_deg_pack<<<dim3(4, 13, T_), 256, 0, stream>>>(A, act_idx, act_cnt, A1, deg);
    k_dinv_u<<<(T_ * BN) / 256, 256, 0, stream>>>(deg, m8, m32, flag, x, act_idx, act_cnt, dinv, u0c, u1c);
    k_c<<<dim3(4, 16, T_), 256, 0, stream>>>(A1, act_cnt, u0c, u1c, c0g, c1g);
    k_gi<<<dim3(100, T_), 384, 0, stream>>>(dinv, c0g, c1g, x, Wg, bg, act_idx, act_cnt, Wih, bih, GI);
    k_gru<<<BN / 16, 384, 0, stream>>>(GI, Whh, bhh, m8, m32, flag, Wfc, bfc, out);
}

// Round 8
// 1344.439 us; speedup vs baseline: 1.2232x; 1.2189x over previous
//
#include <hip/hip_runtime.h>
#include <math.h>

#define T_  20
#define BN  3200
#define H   128
#define N3H 384
#define DOUT 2
#define JW  400          // BN/8 bitpack bytes per t per column (worst case)

typedef unsigned char u8;

// mask may arrive as 1-byte bool or canonicalized int32; flag=1 -> u8.
__device__ __forceinline__ bool getm(const u8* m8, const int* m32, int fl, int idx) {
    return fl ? (m8[idx] != 0) : (m32[idx] != 0);
}

// ---------------------------------------------------------------- K1: detect dtype (local) + compact active rows per t
__global__ __launch_bounds__(256) void k_compact(const u8* __restrict__ m8,
                                                 const int* __restrict__ m32,
                                                 int* __restrict__ flag,
                                                 int* __restrict__ act_idx,
                                                 int* __restrict__ act_cnt) {
    int t = blockIdx.x, tid = threadIdx.x;
    __shared__ int lf;
    if (tid == 0) lf = 0;
    __syncthreads();
    // u8 bool mask: ~1600 ones among 3200 bytes -> some byte at off%4!=0 is set.
    // int32 mask (0/1): bytes at off%4!=0 are always 0.
    bool hit = false;
    for (int j = tid; j < BN; j += 256) {
        if ((j & 3) && m8[t * BN + j]) hit = true;   // (t*BN)%4==0 so idx&3==j&3
    }
    if (__any(hit) && (tid & 63) == 0) atomicOr(&lf, 1);
    __syncthreads();
    int fl = lf;
    if (tid == 0 && fl) atomicOr(flag, 1);           // global flag for later kernels
    for (int j = tid; j < BN; j += 256) {
        if (getm(m8, m32, fl, t * BN + j)) {
            int pos = atomicAdd(&act_cnt[t], 1);     // wave-aggregated by compiler
            act_idx[t * BN + pos] = j;               // unordered: sums order-independent
        }
    }
}

// ---------------------------------------------------------------- K2: column degree + bitpack active-A
// grid (4 colblocks x 13 rowchunks x T), 256 thr; thread = 4 cols via int4.
#define RCH 256
__global__ __launch_bounds__(256) void k_deg_pack(const int* __restrict__ A,
                                                  const int* __restrict__ act_idx,
                                                  const int* __restrict__ act_cnt,
                                                  u8* __restrict__ A1,
                                                  int* __restrict__ deg) {
    int t = blockIdx.z;
    int nact = act_cnt[t];
    int start = blockIdx.y * RCH;
    if (start >= nact) return;                        // uniform: whole block exits
    int n = min(RCH, nact - start);
    __shared__ int ai_s[RCH];
    int tid = threadIdx.x;
    if (tid < n) ai_s[tid] = act_idx[t * BN + start + tid];
    __syncthreads();

    int c = (blockIdx.x * 256 + tid) * 4;
    if (c >= BN) return;                              // after the only barrier: safe
    const int* At = A + (size_t)t * BN * BN;
    u8* A1t = A1 + ((size_t)t * JW + (start >> 3)) * BN + c;
    int cnt0 = 0, cnt1 = 0, cnt2 = 0, cnt3 = 0;
    int n8 = n & ~7;
    int jb = 0;
    for (; jb < n8; jb += 8) {
        unsigned b0 = 0, b1 = 0, b2 = 0, b3 = 0;
        #pragma unroll
        for (int q = 0; q < 8; ++q) {
            int j = ai_s[jb + q];
            int4 aa = *(const int4*)(At + (size_t)j * BN + c);   // 1KB/wave
            cnt0 += aa.x; b0 |= (unsigned)aa.x << q;
            cnt1 += aa.y; b1 |= (unsigned)aa.y << q;
            cnt2 += aa.z; b2 |= (unsigned)aa.z << q;
            cnt3 += aa.w; b3 |= (unsigned)aa.w << q;
        }
        uchar4 pk; pk.x = (u8)b0; pk.y = (u8)b1; pk.z = (u8)b2; pk.w = (u8)b3;
        *(uchar4*)(A1t + (size_t)(jb >> 3) * BN) = pk;
    }
    if (jb < n) {                                     // tail (n not multiple of 8)
        unsigned b0 = 0, b1 = 0, b2 = 0, b3 = 0;
        for (int q = 0; q < n - jb; ++q) {
            int j = ai_s[jb + q];
            int4 aa = *(const int4*)(At + (size_t)j * BN + c);
            cnt0 += aa.x; b0 |= (unsigned)aa.x << q;
            cnt1 += aa.y; b1 |= (unsigned)aa.y << q;
            cnt2 += aa.z; b2 |= (unsigned)aa.z << q;
            cnt3 += aa.w; b3 |= (unsigned)aa.w << q;
        }
        uchar4 pk; pk.x = (u8)b0; pk.y = (u8)b1; pk.z = (u8)b2; pk.w = (u8)b3;
        *(uchar4*)(A1t + (size_t)(jb >> 3) * BN) = pk;
    }
    atomicAdd(&deg[t * BN + c], cnt0);
    atomicAdd(&deg[t * BN + c + 1], cnt1);
    atomicAdd(&deg[t * BN + c + 2], cnt2);
    atomicAdd(&deg[t * BN + c + 3], cnt3);
}

// ---------------------------------------------------------------- K3: compacted u0,u1 (u = rsqrt(deg+1) * x)
__global__ __launch_bounds__(256) void k_u(const int* __restrict__ deg,
                                           const float* __restrict__ x,
                                           const int* __restrict__ act_idx,
                                           const int* __restrict__ act_cnt,
                                           float* __restrict__ u0c,
                                           float* __restrict__ u1c) {
    int idx = blockIdx.x * 256 + threadIdx.x;        // over T_*BN
    int t = idx / BN, r = idx - t * BN;
    float v0 = 0.f, v1 = 0.f;
    if (r < act_cnt[t]) {
        int j = act_idx[idx];                        // = act_idx[t*BN + r]
        float d = rsqrtf((float)(deg[t * BN + j] + 1));  // j active => mask true
        v0 = d * x[(size_t)(t * BN + j) * 2];
        v1 = d * x[(size_t)(t * BN + j) * 2 + 1];
    }
    u0c[idx] = v0;
    u1c[idx] = v1;
}

// ---------------------------------------------------------------- K4: c0[i],c1[i] = sum_j A1[j,i]*u{0,1}[j]
#define JSL 25            // 16 slices x 25 words = 400 >= worst-case nactp
__global__ __launch_bounds__(256) void k_c(const u8* __restrict__ A1,
                                           const int* __restrict__ act_cnt,
                                           const float* __restrict__ u0c,
                                           const float* __restrict__ u1c,
                                           float* __restrict__ c0g,
                                           float* __restrict__ c1g) {
    int t = blockIdx.z, js = blockIdx.y;
    int c = blockIdx.x * 1024 + threadIdx.x * 4;
    if (c >= BN) return;
    int nactp = (act_cnt[t] + 7) >> 3;
    int jw0 = js * JSL, jw1 = min(jw0 + JSL, nactp);
    if (jw0 >= jw1) return;
    const u8* base = A1 + (size_t)t * JW * BN;
    const float* U0 = u0c + t * BN;
    const float* U1 = u1c + t * BN;
    float s0[4] = {0.f, 0.f, 0.f, 0.f}, s1[4] = {0.f, 0.f, 0.f, 0.f};
    for (int jw = jw0; jw < jw1; ++jw) {
        uchar4 aa = *(const uchar4*)(base + (size_t)jw * BN + c);
        unsigned bb[4] = {aa.x, aa.y, aa.z, aa.w};
        const float* Up0 = U0 + jw * 8;
        const float* Up1 = U1 + jw * 8;
        #pragma unroll
        for (int jb = 0; jb < 8; ++jb) {
            float w0 = Up0[jb], w1 = Up1[jb];        // block-uniform -> scalar loads
            #pragma unroll
            for (int k = 0; k < 4; ++k) {
                if ((bb[k] >> jb) & 1) { s0[k] += w0; s1[k] += w1; }
            }
        }
    }
    #pragma unroll
    for (int k = 0; k < 4; ++k) {
        atomicAdd(&c0g[t * BN + c + k], s0[k]);
        atomicAdd(&c1g[t * BN + c + k], s1[k]);
    }
}

// ---------------------------------------------------------------- K5: GI rows for ACTIVE nodes only (compacted)
// grid (200 slotblocks x T), 128 thr: thread = 3 output cols (tid, +128, +256); 16 rows/block.
// Register tiling: 12 FMA per LDS b128 read (was 4) -> LDS-traffic /3, VALU-bound.
__global__ __launch_bounds__(128) void k_gi(const int* __restrict__ deg,
                                            const float* __restrict__ c0g,
                                            const float* __restrict__ c1g,
                                            const float* __restrict__ x,
                                            const float* __restrict__ Wg,
                                            const float* __restrict__ bg,
                                            const int* __restrict__ act_idx,
                                            const int* __restrict__ act_cnt,
                                            const float* __restrict__ Wih,
                                            const float* __restrict__ bih,
                                            float* __restrict__ GI) {
    int t = blockIdx.y;
    int nact = act_cnt[t];
    int sb = blockIdx.x * 16;
    if (sb >= nact) return;                           // uniform
    int ns = min(16, nact - sb);
    __shared__ float gs[16][H];                       // 8 KB
    __shared__ float e0s[16], e1s[16];
    __shared__ int ar[16];
    int tid = threadIdx.x;
    if (tid < 16) {
        int row = 0; float e0 = 0.f, e1 = 0.f;
        if (tid < ns) {
            row = act_idx[t * BN + sb + tid];
            int gi = t * BN + row;
            float d = rsqrtf((float)(deg[gi] + 1));   // active => mask true
            e0 = d * (c0g[gi] + d * x[(size_t)gi * 2]);
            e1 = d * (c1g[gi] + d * x[(size_t)gi * 2 + 1]);
        }
        ar[tid] = row; e0s[tid] = e0; e1s[tid] = e1;
    }
    __syncthreads();
    float wg0 = Wg[tid], wg1 = Wg[H + tid], bgv = bg[tid];
    #pragma unroll
    for (int r = 0; r < 16; ++r)                      // g = relu(e0*Wg0 + e1*Wg1 + bg)
        gs[r][tid] = fmaxf(e0s[r] * wg0 + e1s[r] * wg1 + bgv, 0.f);
    __syncthreads();

    float acc0[16], acc1[16], acc2[16];
    #pragma unroll
    for (int r = 0; r < 16; ++r) { acc0[r] = 0.f; acc1[r] = 0.f; acc2[r] = 0.f; }
    for (int k = 0; k < H; k += 4) {
        float w[4][3];
        #pragma unroll
        for (int kk = 0; kk < 4; ++kk) {
            const float* wr = Wih + (size_t)(k + kk) * N3H;
            w[kk][0] = wr[tid]; w[kk][1] = wr[128 + tid]; w[kk][2] = wr[256 + tid];
        }
        #pragma unroll
        for (int r = 0; r < 16; ++r) {
            float4 g4 = *(const float4*)&gs[r][k];    // LDS broadcast
            acc0[r] += g4.x * w[0][0] + g4.y * w[1][0] + g4.z * w[2][0] + g4.w * w[3][0];
            acc1[r] += g4.x * w[0][1] + g4.y * w[1][1] + g4.z * w[2][1] + g4.w * w[3][1];
            acc2[r] += g4.x * w[0][2] + g4.y * w[1][2] + g4.z * w[2][2] + g4.w * w[3][2];
        }
    }
    float b0 = bih[tid], b1 = bih[128 + tid], b2 = bih[256 + tid];
    #pragma unroll
    for (int r = 0; r < 16; ++r) {
        if (r < ns) {                                 // uniform bound
            size_t bbase = ((size_t)t * BN + ar[r]) * N3H;
            GI[bbase + tid]       = acc0[r] + b0;
            GI[bbase + 128 + tid] = acc1[r] + b1;
            GI[bbase + 256 + tid] = acc2[r] + b2;
        }
    }
}

// ---------------------------------------------------------------- K6: sequential GRU over t + fc output
// 200 blocks x 384 thr (6 waves): thread = one Whh output col, its column held in 128 VGPRs
// (loaded once, coalesced) -> zero W memory traffic inside the t-loop. 16 rows/block.
__global__ __launch_bounds__(384, 1) void k_gru(const float* __restrict__ GI,
                                                const float* __restrict__ Whh,
                                                const float* __restrict__ bhh,
                                                const u8* __restrict__ m8,
                                                const int* __restrict__ m32,
                                                const int* __restrict__ flag,
                                                const float* __restrict__ Wfc,
                                                const float* __restrict__ bfc,
                                                float* __restrict__ out) {
    int row0 = blockIdx.x * 16;
    int tid = threadIdx.x;
    int fl = *flag;
    __shared__ float hs[16][H];                       // 8 KB   (h state across t)
    __shared__ float ghs[16][N3H];                    // 24 KB  (gh per step)
    __shared__ float bhs[N3H];
    __shared__ int ms[16];
    for (int i = tid; i < 16 * H; i += 384) (&hs[0][0])[i] = 0.f;
    bhs[tid] = bhh[tid];
    int lane = tid & 63, wv = tid >> 6;
    float wfa0 = Wfc[lane * 2],        wfa1 = Wfc[lane * 2 + 1];
    float wfb0 = Wfc[(lane + 64) * 2], wfb1 = Wfc[(lane + 64) * 2 + 1];
    float bf0 = bfc[0], bf1 = bfc[1];

    // Whh column -> registers (128 VGPRs), coalesced loads, once per kernel.
    float4 wreg[32];
    #pragma unroll
    for (int kk = 0; kk < 32; ++kk) {
        wreg[kk].x = Whh[(size_t)(4 * kk)     * N3H + tid];
        wreg[kk].y = Whh[(size_t)(4 * kk + 1) * N3H + tid];
        wreg[kk].z = Whh[(size_t)(4 * kk + 2) * N3H + tid];
        wreg[kk].w = Whh[(size_t)(4 * kk + 3) * N3H + tid];
    }

    for (int t = 0; t < T_; ++t) {
        if (tid < 16) ms[tid] = getm(m8, m32, fl, t * BN + row0 + tid) ? 1 : 0;
        __syncthreads();
        int mrl[16];
        #pragma unroll
        for (int r = 0; r < 16; ++r) mrl[r] = ms[r];

        // --- GI prefetch (issued before the matmul; latency hidden under it)
        float pir[6], piz[6], pig[6];
        #pragma unroll
        for (int ii = 0; ii < 6; ++ii) {
            pir[ii] = 0.f; piz[ii] = 0.f; pig[ii] = 0.f;
            int i5 = tid + ii * 384;
            if (i5 < 16 * H) {
                int r = i5 >> 7, u = i5 & 127;
                if (mrl[r]) {                         // guarded: half the HBM traffic
                    size_t gb = ((size_t)t * BN + row0 + r) * N3H;
                    pir[ii] = GI[gb + u];
                    piz[ii] = GI[gb + 128 + u];
                    pig[ii] = GI[gb + 256 + u];
                }
            }
        }

        // --- gh = h @ Whh from register-resident W, active rows only (uniform branch)
        #pragma unroll
        for (int r = 0; r < 16; ++r) {
            if (mrl[r]) {
                float a = 0.f;
                #pragma unroll
                for (int kk = 0; kk < 32; ++kk) {
                    float4 h4 = *(const float4*)&hs[r][kk * 4];   // broadcast
                    float4 w = wreg[kk];
                    a += h4.x * w.x + h4.y * w.y + h4.z * w.z + h4.w * w.w;
                }
                ghs[r][tid] = a;
            }
        }
        __syncthreads();

        // --- pointwise GRU update from prefetched GI
        #pragma unroll
        for (int ii = 0; ii < 6; ++ii) {
            int i5 = tid + ii * 384;
            if (i5 < 16 * H) {
                int r = i5 >> 7, u = i5 & 127;
                if (mrl[r]) {
                    float hr = ghs[r][u] + bhs[u];
                    float hz = ghs[r][128 + u] + bhs[128 + u];
                    float hg = ghs[r][256 + u] + bhs[256 + u];
                    float rg = 1.f / (1.f + expf(-(pir[ii] + hr)));
                    float zg = 1.f / (1.f + expf(-(piz[ii] + hz)));
                    float ng = tanhf(pig[ii] + rg * hg);
                    hs[r][u] = (1.f - zg) * ng + zg * hs[r][u];
                }
            }
        }
        __syncthreads();

        // --- out[row, t, :] = h . Wfc + bfc (post-update h, all rows)
        for (int r = wv; r < 16; r += 6) {
            float h0 = hs[r][lane], h1 = hs[r][lane + 64];
            float p0 = h0 * wfa0 + h1 * wfb0;
            float p1 = h0 * wfa1 + h1 * wfb1;
            for (int o = 32; o > 0; o >>= 1) { p0 += __shfl_down(p0, o); p1 += __shfl_down(p1, o); }
            if (lane == 0) {
                out[((size_t)(row0 + r) * T_ + t) * DOUT]     = p0 + bf0;
                out[((size_t)(row0 + r) * T_ + t) * DOUT + 1] = p1 + bf1;
            }
        }
        __syncthreads();
    }
}

// ---------------------------------------------------------------- launch
extern "C" void kernel_launch(void* const* d_in, const int* in_sizes, int n_in,
                              void* d_out, int out_size, void* d_ws, size_t ws_size,
                              hipStream_t stream) {
    const float* x    = (const float*)d_in[0];
    const int*   A    = (const int*)d_in[1];
    const u8*    m8   = (const u8*)d_in[2];
    const int*   m32  = (const int*)d_in[2];
    const float* Wg   = (const float*)d_in[4];
    const float* bg   = (const float*)d_in[5];
    const float* Wih  = (const float*)d_in[6];
    const float* bih  = (const float*)d_in[7];
    const float* Whh  = (const float*)d_in[8];
    const float* bhh  = (const float*)d_in[9];
    const float* Wfc  = (const float*)d_in[10];
    const float* bfc  = (const float*)d_in[11];
    float* out = (float*)d_out;

    char* ws = (char*)d_ws;
    size_t off = 0;
    auto alloc = [&](size_t bytes) {
        void* p = ws + off;
        off += (bytes + 255) & ~(size_t)255;
        return p;
    };
    // zero-init region (one small memset): flag, act_cnt, deg, c0, c1
    int*   flag    = (int*)alloc(4);
    int*   act_cnt = (int*)alloc(T_ * 4);
    int*   deg     = (int*)alloc((size_t)T_ * BN * 4);
    float* c0g     = (float*)alloc((size_t)T_ * BN * 4);
    float* c1g     = (float*)alloc((size_t)T_ * BN * 4);
    size_t zbytes = off;
    int*   act_idx = (int*)alloc((size_t)T_ * BN * 4);
    float* u0c     = (float*)alloc((size_t)T_ * BN * 4);
    float* u1c     = (float*)alloc((size_t)T_ * BN * 4);
    u8*    A1      = (u8*)alloc((size_t)T_ * JW * BN);         // 25.6 MB bitpacked A
    float* GI      = (float*)alloc((size_t)T_ * BN * N3H * 4); // 98.3 MB (active rows written)

    hipMemsetAsync(ws, 0, zbytes, stream);
    k_compact<<<T_, 256, 0, stream>>>(m8, m32, flag, act_idx, act_cnt);
    k_deg_pack<<<dim3(4, 13, T_), 256, 0, stream>>>(A, act_idx, act_cnt, A1, deg);
    k_u<<<(T_ * BN) / 256, 256, 0, stream>>>(deg, x, act_idx, act_cnt, u0c, u1c);
    k_c<<<dim3(4, 16, T_), 256, 0, stream>>>(A1, act_cnt, u0c, u1c, c0g, c1g);
    k_gi<<<dim3(200, T_), 128, 0, stream>>>(deg, c0g, c1g, x, Wg, bg, act_idx, act_cnt, Wih, bih, GI);
    k_gru<<<BN / 16, 384, 0, stream>>>(GI, Whh, bhh, m8, m32, flag, Wfc, bfc, out);
}